// Round 3
// baseline (1081.877 us; speedup 1.0000x reference)
//
#include <hip/hip_runtime.h>
#include <stdint.h>

#define T_  4096
#define GS  168   // xsr g-stride (floats): 10 u-rows + 8 pad; %32=8 -> 2-way max
#define US  16    // xsr u-stride (floats)
#define AJ  332   // As j-stride (u16): 664B, 8B-aligned; word stride 166%32=6 -> 2-way attn reads
#define AT  40    // As tp-stride (u16)
#define CJ  132   // Cs j-stride (u16): word stride 66%32=2 -> 2-way
#define CS_BASE (64*AJ)

static __device__ __forceinline__ float bflo(uint32_t w){ union{uint32_t u;float f;}v; v.u=w<<16; return v.f; }
static __device__ __forceinline__ float bfhi(uint32_t w){ union{uint32_t u;float f;}v; v.u=w&0xFFFF0000u; return v.f; }
static __device__ __forceinline__ float bf2f(uint16_t u){ union{uint32_t u;float f;}v; v.u=((uint32_t)u)<<16; return v.f; }
static __device__ __forceinline__ uint16_t f2bf(float f){
    union{float f;uint32_t u;}v; v.f=f; uint32_t x=v.u;
    return (uint16_t)((x + 0x7FFFu + ((x>>16)&1u)) >> 16);
}

__global__ __launch_bounds__(1024, 8)
void tamcad_kernel(const float* __restrict__ x, const float* __restrict__ W,
                   const float* __restrict__ bias, float* __restrict__ out)
{
    __shared__ float    xsr[32*GS];            // 21,504 B; x slab / skewed out-stage
    __shared__ uint16_t ACs[64*AJ + 64*CJ];    // 59,392 B; As then Cs
    uint16_t* Asp = ACs;
    uint16_t* Csp = ACs + CS_BASE;

    const int tid   = threadIdx.x;
    const int bk    = blockIdx.x >> 6;   // 0..7
    const int chunk = blockIdx.x & 63;   // 0..63
    const int b     = bk >> 1;
    const int k     = bk & 1;

    // P1 mapping: 32 lanes per group, 3 o's per thread
    const int oq   = tid & 31;
    const int g    = tid >> 5;           // 0..31
    const int slot = oq >> 4;            // 0: t, 1: t+1

    // P0 mapping
    const int dl = tid & 15;
    const int gl = (tid >> 4) & 31;
    const int hl = tid >> 9;             // 0: u0..3, 1: u4..7 + u8

    // ---- per-thread W rows (3 x 16), bias, branchless store routing ----
    float wreg[3][16], breg[3];
    uint32_t sbase[3]; int sstr[3]; bool isl[3];
    #pragma unroll
    for (int r = 0; r < 3; ++r) {
        const int o = oq*3 + r;
        const float4* wp = reinterpret_cast<const float4*>(W + (((size_t)(k*32+g))*96 + o)*16);
        float4 w0=wp[0], w1=wp[1], w2=wp[2], w3=wp[3];
        wreg[r][ 0]=w0.x; wreg[r][ 1]=w0.y; wreg[r][ 2]=w0.z; wreg[r][ 3]=w0.w;
        wreg[r][ 4]=w1.x; wreg[r][ 5]=w1.y; wreg[r][ 6]=w1.z; wreg[r][ 7]=w1.w;
        wreg[r][ 8]=w2.x; wreg[r][ 9]=w2.y; wreg[r][10]=w2.z; wreg[r][11]=w2.w;
        wreg[r][12]=w3.x; wreg[r][13]=w3.y; wreg[r][14]=w3.z; wreg[r][15]=w3.w;
        breg[r] = bias[(k*32+g)*96 + o];
        if (o < 32)      { isl[r]=true;  sbase[r]=o*AJ + g;                     sstr[r]=AT; }
        else if (o < 48) { isl[r]=false; sbase[r]=CS_BASE + g*CJ + (o-32);      sstr[r]=16; }
        else if (o < 80) { isl[r]=true;  sbase[r]=(o-16)*AJ + g;                sstr[r]=AT; }
        else             { isl[r]=false; sbase[r]=CS_BASE + (32+g)*CJ + (o-80); sstr[r]=16; }
    }

    const float* xrow = x + ((size_t)b*1024 + (size_t)(k*32+gl)*16 + dl) * (size_t)T_;

    // ---- register prefetch of the first slab: hl=0 -> u0..3, hl=1 -> u4..7 + u8 ----
    float4 pA; float pS = 0.0f;
    {
        const float* gp = xrow + chunk*64 + hl*4;
        pA = *(const float4*)gp;
        pS = (hl && (chunk*64 + 8) < T_) ? gp[4] : 0.0f;
    }

    for (int l = 0; l < 8; ++l) {
        const int t0 = chunk*64 + l*8;

        // ---- P0: spill prefetched regs into xsr[g][u][d] ----
        {
            float* xp = xsr + gl*GS + dl;
            const int ub = hl*4;
            xp[(ub+0)*US]=pA.x; xp[(ub+1)*US]=pA.y; xp[(ub+2)*US]=pA.z; xp[(ub+3)*US]=pA.w;
            if (hl) xp[8*US] = pS;
        }
        __syncthreads();

        // issue next tile's global loads; in flight across P1/P3/P4
        if (l < 7) {
            const int t0n = t0 + 8;
            const float* gp = xrow + t0n + hl*4;
            pA = *(const float4*)gp;
            pS = (hl && (t0n + 8) < T_) ? gp[4] : 0.0f;
        }

        // ---- P1: y = W·x + b, no-max softmax over 32-lane group ----
        {
            float xv[16];
            {
                const float4* p4 = reinterpret_cast<const float4*>(xsr + g*GS + slot*US);
                float4 A0=p4[0], A1=p4[1], A2=p4[2], A3=p4[3];
                xv[ 0]=A0.x; xv[ 1]=A0.y; xv[ 2]=A0.z; xv[ 3]=A0.w;
                xv[ 4]=A1.x; xv[ 5]=A1.y; xv[ 6]=A1.z; xv[ 7]=A1.w;
                xv[ 8]=A2.x; xv[ 9]=A2.y; xv[10]=A2.z; xv[11]=A2.w;
                xv[12]=A3.x; xv[13]=A3.y; xv[14]=A3.z; xv[15]=A3.w;
            }
            for (int tp = 0; tp < 8; ++tp) {
                float yv[3];
                #pragma unroll
                for (int r = 0; r < 3; ++r) {
                    float a = breg[r];
                    #pragma unroll
                    for (int d = 0; d < 16; ++d) a = fmaf(wreg[r][d], xv[d], a);
                    yv[r] = a;
                }
                // prefetch next tp's x row (GS pad covers tp=7 overread)
                {
                    const float4* p4 = reinterpret_cast<const float4*>(xsr + g*GS + (tp+1+slot)*US);
                    float4 A0=p4[0], A1=p4[1], A2=p4[2], A3=p4[3];
                    xv[ 0]=A0.x; xv[ 1]=A0.y; xv[ 2]=A0.z; xv[ 3]=A0.w;
                    xv[ 4]=A1.x; xv[ 5]=A1.y; xv[ 6]=A1.z; xv[ 7]=A1.w;
                    xv[ 8]=A2.x; xv[ 9]=A2.y; xv[10]=A2.z; xv[11]=A2.w;
                    xv[12]=A3.x; xv[13]=A3.y; xv[14]=A3.z; xv[15]=A3.w;
                }
                // softmax without max subtraction (|y| <~ 8, fp32-safe)
                float ev[3]; float ssum = 0.0f;
                #pragma unroll
                for (int r = 0; r < 3; ++r) {
                    ev[r] = __expf(yv[r]);
                    ssum += isl[r] ? ev[r] : 0.0f;
                }
                #pragma unroll
                for (int s = 1; s < 32; s <<= 1) ssum += __shfl_xor(ssum, s);
                const float rinv = __builtin_amdgcn_rcpf(ssum);
                #pragma unroll
                for (int r = 0; r < 3; ++r) {
                    const float sv = isl[r] ? ev[r]*rinv : yv[r];
                    ACs[sbase[r] + tp*sstr[r]] = f2bf(sv);
                }
            }
        }
        __syncthreads();

        // ---- P3: out[i][d] = sum_j A[i][j]*C[j][d]; 8 waves, one per t ----
        if (tid < 512) {
            const int t  = tid >> 6;            // 0..7
            const int r6 = tid & 63;
            const int i0 = (r6 & 7) << 2;       // 0,4,..28
            const int d0 = (r6 >> 3) << 1;      // 0,2,..14
            float acc[4][2];
            #pragma unroll
            for (int ii = 0; ii < 4; ++ii) { acc[ii][0]=0.f; acc[ii][1]=0.f; }
            const uint16_t* Ap = Asp + t*AT + i0;
            const uint16_t* Cp = Csp + t*16 + d0;
            #pragma unroll 8
            for (int j = 0; j < 64; ++j) {
                uint2    aw = *(const uint2*)(Ap + j*AJ);
                uint32_t cw = *(const uint32_t*)(Cp + j*CJ);
                float a0=bflo(aw.x), a1=bfhi(aw.x), a2=bflo(aw.y), a3=bfhi(aw.y);
                float c0=bflo(cw),   c1=bfhi(cw);
                acc[0][0]=fmaf(a0,c0,acc[0][0]); acc[0][1]=fmaf(a0,c1,acc[0][1]);
                acc[1][0]=fmaf(a1,c0,acc[1][0]); acc[1][1]=fmaf(a1,c1,acc[1][1]);
                acc[2][0]=fmaf(a2,c0,acc[2][0]); acc[2][1]=fmaf(a2,c1,acc[2][1]);
                acc[3][0]=fmaf(a3,c0,acc[3][0]); acc[3][1]=fmaf(a3,c1,acc[3][1]);
            }
            #pragma unroll
            for (int ii = 0; ii < 4; ++ii)
                #pragma unroll
                for (int dd = 0; dd < 2; ++dd) {
                    const int row = (i0+ii)*16 + d0+dd;
                    xsr[row*9 + ((t + (row>>6)) & 7)] = acc[ii][dd];
                }
        }
        __syncthreads();

        // ---- P4: t-coalesced 32B-row global writes ----
        {
            if (tid < 512) {
                const int sk = tid >> 6;
                float ov[8];
                #pragma unroll
                for (int u = 0; u < 8; ++u) ov[u] = xsr[tid*9 + ((u + sk) & 7)];
                float* op = out + ((size_t)b*1024 + k*512 + tid)*(size_t)T_ + t0;
                *(float4*)(op + 0) = make_float4(ov[0],ov[1],ov[2],ov[3]);
                *(float4*)(op + 4) = make_float4(ov[4],ov[5],ov[6],ov[7]);
            }
            float* attn_base = out + (size_t)4*1024*(size_t)T_;
            #pragma unroll
            for (int rr = 0; rr < 2; ++rr) {
                const int q = tid + 1024*rr;
                const int i = q >> 6;
                const int j = q & 63;
                const uint16_t* ap = Asp + j*AJ + i;
                float av[8];
                #pragma unroll
                for (int u = 0; u < 8; ++u) av[u] = bf2f(ap[u*AT]);
                float* tp2 = attn_base + (((size_t)bk*32 + i)*64 + j)*(size_t)T_ + t0;
                *(float4*)(tp2 + 0) = make_float4(av[0],av[1],av[2],av[3]);
                *(float4*)(tp2 + 4) = make_float4(av[4],av[5],av[6],av[7]);
            }
        }
        __syncthreads();
    }
}

extern "C" void kernel_launch(void* const* d_in, const int* in_sizes, int n_in,
                              void* d_out, int out_size, void* d_ws, size_t ws_size,
                              hipStream_t stream) {
    const float* x  = (const float*)d_in[0];
    const float* W  = (const float*)d_in[1];
    const float* bs = (const float*)d_in[2];
    float* out = (float*)d_out;
    tamcad_kernel<<<dim3(512), dim3(1024), 0, stream>>>(x, W, bs, out);
}

// Round 4
// 345.922 us; speedup vs baseline: 3.1275x; 3.1275x over previous
//
#include <hip/hip_runtime.h>
#include <stdint.h>

#define T_  4096
#define GS  296   // xsr g-stride (floats); %32 = 8 -> 2-way max
#define US  16    // xsr u-stride (floats)
#define AJ  652   // As j-stride (u16): 1304B, 8B-aligned; word stride 326%32=6
#define AT  40    // As tp-stride (u16)
#define CJ  260   // Cs j-stride (u16): word stride 130%32=2

static __device__ __forceinline__ float bflo(uint32_t w){ union{uint32_t u;float f;}v; v.u=w<<16; return v.f; }
static __device__ __forceinline__ float bfhi(uint32_t w){ union{uint32_t u;float f;}v; v.u=w&0xFFFF0000u; return v.f; }
static __device__ __forceinline__ uint16_t f2bf(float f){
    union{float f;uint32_t u;}v; v.f=f; uint32_t x=v.u;
    return (uint16_t)((x + 0x7FFFu + ((x>>16)&1u)) >> 16);
}

__global__ __launch_bounds__(1024, 4)
void tamcad_kernel(const float* __restrict__ x, const float* __restrict__ W,
                   const float* __restrict__ bias, float* __restrict__ out)
{
    __shared__ float    xsr[32*GS];   // 37,888 B; x slab / skewed out-stage
    __shared__ uint16_t As [64*AJ];   // 83,456 B; A[j*AJ + tp*AT + i] (bf16)
    __shared__ uint16_t Cs [64*CJ];   // 33,280 B; C[j*CJ + tp*16 + d] (bf16)

    const int tid   = threadIdx.x;
    const int bk    = blockIdx.x >> 5;   // 0..7
    const int chunk = blockIdx.x & 31;   // 0..31
    const int b     = bk >> 1;
    const int k     = bk & 1;

    // P1 mapping: 32 lanes per group, 3 o's per thread
    const int oq   = tid & 31;
    const int g    = tid >> 5;           // 0..31
    const int slot = oq >> 4;            // 0: t, 1: t+1

    // P0 mapping
    const int dl = tid & 15;
    const int gl = (tid >> 4) & 31;
    const int hl = tid >> 9;             // 0: u0..7, 1: u8..16

    // ---- per-thread W rows (3 x 16), bias, routing ----
    float wreg[3][16], breg[3];
    int aoff[3], coff[3]; bool isl[3];
    #pragma unroll
    for (int r = 0; r < 3; ++r) {
        const int o = oq*3 + r;
        const float4* wp = reinterpret_cast<const float4*>(W + (((size_t)(k*32+g))*96 + o)*16);
        float4 w0=wp[0], w1=wp[1], w2=wp[2], w3=wp[3];
        wreg[r][ 0]=w0.x; wreg[r][ 1]=w0.y; wreg[r][ 2]=w0.z; wreg[r][ 3]=w0.w;
        wreg[r][ 4]=w1.x; wreg[r][ 5]=w1.y; wreg[r][ 6]=w1.z; wreg[r][ 7]=w1.w;
        wreg[r][ 8]=w2.x; wreg[r][ 9]=w2.y; wreg[r][10]=w2.z; wreg[r][11]=w2.w;
        wreg[r][12]=w3.x; wreg[r][13]=w3.y; wreg[r][14]=w3.z; wreg[r][15]=w3.w;
        breg[r] = bias[(k*32+g)*96 + o];
        if (o < 32)      { isl[r]=true;  aoff[r]=o*AJ + g;            coff[r]=0; }
        else if (o < 48) { isl[r]=false; coff[r]=g*CJ + (o-32);       aoff[r]=0; }
        else if (o < 80) { isl[r]=true;  aoff[r]=(o-16)*AJ + g;       coff[r]=0; }
        else             { isl[r]=false; coff[r]=(32+g)*CJ + (o-80);  aoff[r]=0; }
    }

    const float* xrow = x + ((size_t)b*1024 + (size_t)(k*32+gl)*16 + dl) * (size_t)T_;

    // ---- register prefetch of the first x slab ----
    float4 pA, pB; float pS = 0.0f;
    {
        const float* gp = xrow + chunk*128 + hl*8;
        pA = *(const float4*)(gp + 0);
        pB = *(const float4*)(gp + 4);
        pS = (hl && (chunk*128 + 16) < T_) ? gp[8] : 0.0f;
    }

    for (int l = 0; l < 8; ++l) {
        const int t0 = chunk*128 + l*16;

        // ---- P0: spill prefetched regs into xsr[g][u][d] ----
        {
            float* xp = xsr + gl*GS + dl;
            const int ub = hl*8;
            xp[(ub+0)*US]=pA.x; xp[(ub+1)*US]=pA.y; xp[(ub+2)*US]=pA.z; xp[(ub+3)*US]=pA.w;
            xp[(ub+4)*US]=pB.x; xp[(ub+5)*US]=pB.y; xp[(ub+6)*US]=pB.z; xp[(ub+7)*US]=pB.w;
            if (hl) xp[16*US] = pS;
        }
        __syncthreads();

        // issue next tile's loads; in flight across P1/P3/P4
        if (l < 7) {
            const int t0n = t0 + 16;
            const float* gp = xrow + t0n + hl*8;
            pA = *(const float4*)(gp + 0);
            pB = *(const float4*)(gp + 4);
            pS = (hl && (t0n + 16) < T_) ? gp[8] : 0.0f;
        }

        // ---- P1: y = W·x + b; softmax with 8-wide batched shuffle reduction ----
        #pragma unroll
        for (int th = 0; th < 2; ++th) {
            float ev0[8], ev1[8], ev2[8], asum[8];
            #pragma unroll
            for (int q = 0; q < 8; ++q) {
                const int tp = th*8 + q;
                float xv[16];
                {
                    const float4* p4 = reinterpret_cast<const float4*>(xsr + g*GS + (tp+slot)*US);
                    float4 A0=p4[0], A1=p4[1], A2=p4[2], A3=p4[3];
                    xv[ 0]=A0.x; xv[ 1]=A0.y; xv[ 2]=A0.z; xv[ 3]=A0.w;
                    xv[ 4]=A1.x; xv[ 5]=A1.y; xv[ 6]=A1.z; xv[ 7]=A1.w;
                    xv[ 8]=A2.x; xv[ 9]=A2.y; xv[10]=A2.z; xv[11]=A2.w;
                    xv[12]=A3.x; xv[13]=A3.y; xv[14]=A3.z; xv[15]=A3.w;
                }
                float y0 = breg[0], y1 = breg[1], y2 = breg[2];
                #pragma unroll
                for (int d = 0; d < 16; ++d) {
                    y0 = fmaf(wreg[0][d], xv[d], y0);
                    y1 = fmaf(wreg[1][d], xv[d], y1);
                    y2 = fmaf(wreg[2][d], xv[d], y2);
                }
                // no-max softmax (|y| <~ 8, fp32-safe)
                const float e0 = __expf(y0), e1 = __expf(y1), e2 = __expf(y2);
                asum[q] = (isl[0]?e0:0.f) + (isl[1]?e1:0.f) + (isl[2]?e2:0.f);
                if (!isl[0]) Cs[coff[0] + tp*16] = f2bf(y0);
                if (!isl[1]) Cs[coff[1] + tp*16] = f2bf(y1);
                if (!isl[2]) Cs[coff[2] + tp*16] = f2bf(y2);
                ev0[q]=e0; ev1[q]=e1; ev2[q]=e2;
            }
            // 5 rounds x 8 independent chains (pipelined cross-lane reduce)
            #pragma unroll
            for (int s = 1; s < 32; s <<= 1) {
                #pragma unroll
                for (int q = 0; q < 8; ++q) asum[q] += __shfl_xor(asum[q], s);
            }
            #pragma unroll
            for (int q = 0; q < 8; ++q) {
                const int tp = th*8 + q;
                const float rinv = __builtin_amdgcn_rcpf(asum[q]);
                if (isl[0]) As[aoff[0] + tp*AT] = f2bf(ev0[q]*rinv);
                if (isl[1]) As[aoff[1] + tp*AT] = f2bf(ev1[q]*rinv);
                if (isl[2]) As[aoff[2] + tp*AT] = f2bf(ev2[q]*rinv);
            }
        }
        __syncthreads();

        // ---- P3: out[i][d] = sum_j A[i][j]*C[j][d]; one wave per t ----
        {
            const int t  = tid >> 6;            // 0..15
            const int r6 = tid & 63;
            const int i0 = (r6 & 7) << 2;       // 0,4,..28
            const int d0 = (r6 >> 3) << 1;      // 0,2,..14
            float acc[4][2];
            #pragma unroll
            for (int ii = 0; ii < 4; ++ii) { acc[ii][0]=0.f; acc[ii][1]=0.f; }
            const uint16_t* Ap = As + t*AT + i0;
            const uint16_t* Cp = Cs + t*16 + d0;
            #pragma unroll 8
            for (int j = 0; j < 64; ++j) {
                uint2    aw = *(const uint2*)(Ap + j*AJ);
                uint32_t cw = *(const uint32_t*)(Cp + j*CJ);
                float a0=bflo(aw.x), a1=bfhi(aw.x), a2=bflo(aw.y), a3=bfhi(aw.y);
                float c0=bflo(cw),   c1=bfhi(cw);
                acc[0][0]=fmaf(a0,c0,acc[0][0]); acc[0][1]=fmaf(a0,c1,acc[0][1]);
                acc[1][0]=fmaf(a1,c0,acc[1][0]); acc[1][1]=fmaf(a1,c1,acc[1][1]);
                acc[2][0]=fmaf(a2,c0,acc[2][0]); acc[2][1]=fmaf(a2,c1,acc[2][1]);
                acc[3][0]=fmaf(a3,c0,acc[3][0]); acc[3][1]=fmaf(a3,c1,acc[3][1]);
            }
            const int skew = i0;                // == (row>>6)*4 for all rows written
            #pragma unroll
            for (int ii = 0; ii < 4; ++ii)
                #pragma unroll
                for (int dd = 0; dd < 2; ++dd) {
                    const int row = (i0+ii)*16 + d0+dd;
                    xsr[row*17 + skew + t] = acc[ii][dd];
                }
        }
        __syncthreads();

        // ---- P4: split halves; t-coalesced 64B-row global writes ----
        if (tid < 512) {
            const int skew = (tid >> 6) * 4;
            float ov[16];
            #pragma unroll
            for (int u = 0; u < 16; ++u) ov[u] = xsr[tid*17 + skew + u];
            float* op = out + ((size_t)b*1024 + k*512 + tid)*(size_t)T_ + t0;
            *(float4*)(op + 0)  = make_float4(ov[ 0],ov[ 1],ov[ 2],ov[ 3]);
            *(float4*)(op + 4)  = make_float4(ov[ 4],ov[ 5],ov[ 6],ov[ 7]);
            *(float4*)(op + 8)  = make_float4(ov[ 8],ov[ 9],ov[10],ov[11]);
            *(float4*)(op + 12) = make_float4(ov[12],ov[13],ov[14],ov[15]);
        } else {
            // 4 attn rows per thread via b64 quad reads (2 lanes/bank -> conflict-free)
            const int q  = tid - 512;
            const int j  = q & 63;
            const int i0 = (q >> 6) << 2;       // 0,4,..28
            float* attn_base = out + (size_t)4*1024*(size_t)T_;
            const uint16_t* ap = As + j*AJ + i0;
            float* tp0 = attn_base + (((size_t)bk*32 + i0)*64 + j)*(size_t)T_ + t0;
            #pragma unroll
            for (int c = 0; c < 4; ++c) {       // tp chunks of 4
                float av[4][4];
                #pragma unroll
                for (int u = 0; u < 4; ++u) {
                    uint2 aw = *(const uint2*)(ap + (c*4+u)*AT);
                    av[0][u]=bflo(aw.x); av[1][u]=bfhi(aw.x);
                    av[2][u]=bflo(aw.y); av[3][u]=bfhi(aw.y);
                }
                #pragma unroll
                for (int ii = 0; ii < 4; ++ii)
                    *(float4*)(tp0 + (size_t)ii*64*T_ + c*4) =
                        make_float4(av[ii][0],av[ii][1],av[ii][2],av[ii][3]);
            }
        }
        __syncthreads();
    }
}

extern "C" void kernel_launch(void* const* d_in, const int* in_sizes, int n_in,
                              void* d_out, int out_size, void* d_ws, size_t ws_size,
                              hipStream_t stream) {
    const float* x  = (const float*)d_in[0];
    const float* W  = (const float*)d_in[1];
    const float* bs = (const float*)d_in[2];
    float* out = (float*)d_out;
    tamcad_kernel<<<dim3(256), dim3(1024), 0, stream>>>(x, W, bs, out);
}